// Round 10
// baseline (5185.501 us; speedup 1.0000x reference)
//
#include <hip/hip_runtime.h>
#include <hip/hip_bf16.h>

#define BB 256      // batch
#define CC 2048     // code_num
#define HD 1024     // hidden
#define TT 64       // max_len
#define H3 3072
#define NBLK 512
#define NGRP 16     // groups of batch rows
#define GBLK 32     // blocks (col-splits) per group
#define GROWS 16    // batch rows per group

typedef __attribute__((ext_vector_type(8)))  short bf16x8;
typedef __attribute__((ext_vector_type(4)))  float f32x4;
typedef __attribute__((ext_vector_type(4)))  int   i32x4;

__device__ __forceinline__ float sigmoidf_(float x){ return 1.0f/(1.0f+__expf(-x)); }
__device__ __forceinline__ float tanhf_(float x){ float e=__expf(2.0f*x); return 1.0f - 2.0f/(e+1.0f); }
__device__ __forceinline__ unsigned short bfbits(float x){
  __hip_bfloat16 b = __float2bfloat16(x);
  return *reinterpret_cast<unsigned short*>(&b);
}
__device__ __forceinline__ void st_sys_bf16(__hip_bfloat16* p, float v){
  __hip_atomic_store((unsigned short*)p, bfbits(v), __ATOMIC_RELAXED, __HIP_MEMORY_SCOPE_SYSTEM);
}
__device__ __forceinline__ bf16x8 ldfrag(const __hip_bfloat16* p){
  return *reinterpret_cast<const bf16x8*>(p);
}
// 16B system-coherent load (L2-bypass). Must waitv0() before consuming.
__device__ __forceinline__ i32x4 ld_sys16(const void* p){
  i32x4 r;
  asm volatile("global_load_dwordx4 %0, %1, off sc0 sc1"
               : "=v"(r) : "v"(p) : "memory");
  return r;
}
__device__ __forceinline__ void waitv0(){
  asm volatile("s_waitcnt vmcnt(0)" ::: "memory");
  __builtin_amdgcn_sched_barrier(0);
}
// RELEASE: flush dirty L2 lines to the coherence point, no invalidate.
__device__ __forceinline__ void release_wb(){
  asm volatile("s_waitcnt vmcnt(0)\n\t"
               "buffer_wbl2 sc1\n\t"
               "s_waitcnt vmcnt(0)" ::: "memory");
}

__global__ void cvt_f32_bf16(const float* __restrict__ in, __hip_bfloat16* __restrict__ out, int n){
  int i = (blockIdx.x*blockDim.x + threadIdx.x)*4;
  int stride = gridDim.x*blockDim.x*4;
  for (; i < n; i += stride){
    float4 v = *reinterpret_cast<const float4*>(in + i);
    ushort4 s;
    s.x = bfbits(v.x); s.y = bfbits(v.y); s.z = bfbits(v.z); s.w = bfbits(v.w);
    *reinterpret_cast<ushort4*>(out + i) = s;
  }
}

#define MFMA16(a,b,c) __builtin_amdgcn_mfma_f32_16x16x32_bf16((a),(b),(c),0,0,0)

// Persistent GRU, 512 blocks x 1024 threads, 2 blocks/CU (VGPR<=64 via
// launch_bounds, LDS 50KB). bid = bsub(bid&31) col-split + g(bid>>5) group.
// Group g owns batch rows [g*16,+16); bsub owns 32 H-cols / 64 C-cols.
// 2 blocks/CU => while one block stalls on flags/L3 staging, the co-resident
// block computes (the round-9 structure was 1 block/CU and latency-serial).
// Waves: 0..11 compute, 12..15 stage act K-chunks (16KB dbuf) concurrently;
// 12,13 also do the gate epilogue and hold h in registers across steps.
__global__ __launch_bounds__(1024, 8) void gru_persistent(
    const __hip_bfloat16* __restrict__ wih,     // [3H][C]
    const __hip_bfloat16* __restrict__ whh,     // [3H][H]
    const __hip_bfloat16* __restrict__ wout,    // [C][H]
    const __hip_bfloat16* __restrict__ noise16, // [B][H]
    const float* __restrict__ bih,
    const float* __restrict__ bhh,
    const float* __restrict__ bout,
    float* __restrict__ samples,                // [B][T][C]
    float* __restrict__ hiddens,                // [B][T][H]
    __hip_bfloat16* cb0, __hip_bfloat16* cb1,   // [B][C] codes ping-pong
    __hip_bfloat16* hb0, __hip_bfloat16* hb1,   // [B][H] h ping-pong
    unsigned* flagC, unsigned* flagH)
{
  __shared__ __align__(16) char  chunkbuf[2][16384]; // A-frag panels, dbuf
  __shared__ __align__(16) float dumpbuf[12*64*4];   // Y cross-ks reduce
  __shared__ __align__(16) float ghbuf[6*64*4];      // X->Y gh exchange

  const int tid  = threadIdx.x;
  const int lane = tid & 63;
  const int wid  = tid >> 6;      // 0..15
  const int bid  = blockIdx.x;
  const int g    = bid >> 5;      // group (batch rows)
  const int bsub = bid & 31;      // col-split
  const int rl   = lane & 15;
  const int kg   = lane >> 4;     // 0..3

  auto signal = [&](unsigned* flags, unsigned gen){
    __syncthreads();
    if (tid == 0){
      release_wb();
      __hip_atomic_store(&flags[g*GBLK + bsub], gen, __ATOMIC_RELAXED, __HIP_MEMORY_SCOPE_SYSTEM);
    }
  };
  auto waitf = [&](unsigned* flags, unsigned gen){
    if (tid < GBLK){
      while (__hip_atomic_load(&flags[g*GBLK + tid], __ATOMIC_RELAXED, __HIP_MEMORY_SCOPE_SYSTEM) < gen)
        __builtin_amdgcn_s_sleep(2);
    }
    __syncthreads();
  };

  // Stage one 16KB act chunk (16 rows x 512 k) as 16 A-frag panels (1KB each:
  // lane l -> row l&15, k-elems (l>>4)*8 of a 32-k window). Stager waves only.
  auto stageChunk = [&](const __hip_bfloat16* src, int RS, int kbase, int bufsel){
    if (wid >= 12){
      const int sw = wid - 12;
      i32x4 r0, r1, r2, r3;
      const __hip_bfloat16* base = src + (size_t)(g*GROWS + rl)*RS + kbase + kg*8;
      r0 = ld_sys16(base + (sw*4+0)*32);
      r1 = ld_sys16(base + (sw*4+1)*32);
      r2 = ld_sys16(base + (sw*4+2)*32);
      r3 = ld_sys16(base + (sw*4+3)*32);
      waitv0();
      char* b = chunkbuf[bufsel] + lane*16;
      *(i32x4*)(b + (sw*4+0)*1024) = r0;
      *(i32x4*)(b + (sw*4+1)*1024) = r1;
      *(i32x4*)(b + (sw*4+2)*1024) = r2;
      *(i32x4*)(b + (sw*4+3)*1024) = r3;
    }
  };

  float hp[4] = {0.f, 0.f, 0.f, 0.f};   // this block's h slice (waves 12,13)

  // ---------------- phase X: codes_t + gh_t from h_t (noise at t=0) --------
  auto phaseX = [&](const __hip_bfloat16* hsrc, __hip_bfloat16* codesDst, int t){
    stageChunk(hsrc, HD, 0, 0);
    __syncthreads();
    f32x4 acc = {0.f,0.f,0.f,0.f};
    const __hip_bfloat16* wl = nullptr;
    if (wid < 4){
      wl = wout + (size_t)(bsub*64 + wid*16 + rl)*HD + kg*8;
    } else if (wid < 10){
      const int gate = (wid-4) >> 1, ch = (wid-4) & 1;
      wl = whh + (size_t)(gate*HD + bsub*32 + ch*16 + rl)*HD + kg*8;
    }
    const bool act = (wid < 4) || (wid < 10 && t > 0);   // gh is 0 at t=0
#pragma unroll 1
    for (int c = 0; c < 2; c++){
      if (c == 0) stageChunk(hsrc, HD, 512, 1);
      if (act){
#pragma unroll
        for (int p = 0; p < 16; p++){
          bf16x8 a = *(const bf16x8*)(chunkbuf[c] + p*1024 + lane*16);
          acc = MFMA16(a, ldfrag(wl + c*512 + p*32), acc);
        }
      }
      __syncthreads();
    }
    if (wid < 4){
      const int col = bsub*64 + wid*16 + rl;
      const float bo = bout[col];
#pragma unroll
      for (int q = 0; q < 4; q++){
        const int brow = g*GROWS + kg*4 + q;
        float sv = sigmoidf_(acc[q] + bo);
        __builtin_nontemporal_store(sv, &samples[(size_t)brow*TT*CC + (size_t)t*CC + col]);
        st_sys_bf16(codesDst + (size_t)brow*CC + col, sv);
      }
    } else if (wid < 10){
      f32x4 out = (t == 0) ? (f32x4){0.f,0.f,0.f,0.f} : acc;
      *(f32x4*)&ghbuf[((wid-4)*64 + lane)*4] = out;
    }
  };

  // ---------------- phase Y: gi + combine -> h_{t+1} -----------------------
  auto phaseY = [&](const __hip_bfloat16* codesSrc, __hip_bfloat16* hDst, int t){
    stageChunk(codesSrc, CC, 0, 0);
    __syncthreads();
    f32x4 acc = {0.f,0.f,0.f,0.f};
    const __hip_bfloat16* wl = nullptr;
    int ks = 0;
    if (wid < 12){
      const int ct = wid >> 1;        // 0..5 = gate*2 + colhalf
      ks = wid & 1;                   // K-half
      const int gate = ct >> 1, ch = ct & 1;
      wl = wih + (size_t)(gate*HD + bsub*32 + ch*16 + rl)*CC + kg*8;
    }
#pragma unroll 1
    for (int c = 0; c < 4; c++){
      if (c < 3) stageChunk(codesSrc, CC, (c+1)*512, (c+1)&1);
      if (wid < 12 && (c >> 1) == ks){
#pragma unroll
        for (int p = 0; p < 16; p++){
          bf16x8 a = *(const bf16x8*)(chunkbuf[c&1] + p*1024 + lane*16);
          acc = MFMA16(a, ldfrag(wl + c*512 + p*32), acc);
        }
      }
      __syncthreads();
    }
    if (wid < 12) *(f32x4*)&dumpbuf[(wid*64 + lane)*4] = acc;
    __syncthreads();

    if (wid == 12 || wid == 13){
      const int ch   = wid - 12;
      const int jcol = bsub*32 + ch*16 + rl;
      const float bI0 = bih[jcol], bI1 = bih[jcol+HD], bI2 = bih[jcol+2*HD];
      const float bH0 = bhh[jcol], bH1 = bhh[jcol+HD], bH2 = bhh[jcol+2*HD];
      f32x4 gi[3], gh[3];
#pragma unroll
      for (int gate = 0; gate < 3; gate++){
        const int ct = gate*2 + ch;
        f32x4 a0 = *(const f32x4*)&dumpbuf[((ct*2+0)*64 + lane)*4];
        f32x4 a1 = *(const f32x4*)&dumpbuf[((ct*2+1)*64 + lane)*4];
        gi[gate] = (f32x4){a0[0]+a1[0], a0[1]+a1[1], a0[2]+a1[2], a0[3]+a1[3]};
        gh[gate] = *(const f32x4*)&ghbuf[((gate*2+ch)*64 + lane)*4];
      }
#pragma unroll
      for (int q = 0; q < 4; q++){
        const int brow = g*GROWS + kg*4 + q;
        float r = sigmoidf_(gi[0][q] + gh[0][q] + bI0 + bH0);
        float z = sigmoidf_(gi[1][q] + gh[1][q] + bI1 + bH1);
        float n = tanhf_(gi[2][q] + bI2 + r*(gh[2][q] + bH2));
        float hv = (1.0f - z)*n + z*hp[q];
        hp[q] = hv;                    // keep own h slice in registers
        __builtin_nontemporal_store(hv, &hiddens[(size_t)brow*TT*HD + (size_t)t*HD + jcol]);
        st_sys_bf16(hDst + (size_t)brow*HD + jcol, hv);
      }
    }
  };

  // ---------------- sequence ----------------
#pragma unroll 1
  for (int t = 0; t < TT; t++){
    const __hip_bfloat16* hsrc = (t & 1) ? hb0 : hb1;   // h_t (from Y(t-1))
    __hip_bfloat16* codesCur   = (t & 1) ? cb1 : cb0;
    __hip_bfloat16* hDst       = (t & 1) ? hb1 : hb0;   // h_{t+1}

    if (t > 0) waitf(flagH, (unsigned)t);
    phaseX((t == 0) ? noise16 : hsrc, codesCur, t);
    signal(flagC, (unsigned)(t+1));

    waitf(flagC, (unsigned)(t+1));
    phaseY(codesCur, hDst, t);
    signal(flagH, (unsigned)(t+1));
  }
}

extern "C" void kernel_launch(void* const* d_in, const int* in_sizes, int n_in,
                              void* d_out, int out_size, void* d_ws, size_t ws_size,
                              hipStream_t stream) {
  const float* noise = (const float*)d_in[0];
  const float* W_ih  = (const float*)d_in[1];
  const float* b_ih  = (const float*)d_in[2];
  const float* W_hh  = (const float*)d_in[3];
  const float* b_hh  = (const float*)d_in[4];
  const float* W_out = (const float*)d_in[5];
  const float* b_out = (const float*)d_in[6];

  float* samples = (float*)d_out;                       // [B][T][C]
  float* hiddens = samples + (size_t)BB*TT*CC;          // [B][T][H]

  char* w = (char*)d_ws;
  unsigned* flagC = (unsigned*)w;              w += 2048;   // 512 u32
  unsigned* flagH = (unsigned*)w;              w += 2048;
  __hip_bfloat16* wih16 = (__hip_bfloat16*)w;  w += (size_t)H3*CC*2;
  __hip_bfloat16* whh16 = (__hip_bfloat16*)w;  w += (size_t)H3*HD*2;
  __hip_bfloat16* wout16= (__hip_bfloat16*)w;  w += (size_t)CC*HD*2;
  __hip_bfloat16* noise16=(__hip_bfloat16*)w;  w += (size_t)BB*HD*2;
  __hip_bfloat16* cb0   = (__hip_bfloat16*)w;  w += (size_t)BB*CC*2;
  __hip_bfloat16* cb1   = (__hip_bfloat16*)w;  w += (size_t)BB*CC*2;
  __hip_bfloat16* hb0   = (__hip_bfloat16*)w;  w += (size_t)BB*HD*2;
  __hip_bfloat16* hb1   = (__hip_bfloat16*)w;  w += (size_t)BB*HD*2;

  hipMemsetAsync(flagC, 0, 4096, stream);
  cvt_f32_bf16<<<2048, 256, 0, stream>>>(W_ih,  wih16,  H3*CC);
  cvt_f32_bf16<<<2048, 256, 0, stream>>>(W_hh,  whh16,  H3*HD);
  cvt_f32_bf16<<<1024, 256, 0, stream>>>(W_out, wout16, CC*HD);
  cvt_f32_bf16<<<256,  256, 0, stream>>>(noise, noise16, BB*HD);

  gru_persistent<<<NBLK, 1024, 0, stream>>>(
      wih16, whh16, wout16, noise16, b_ih, b_hh, b_out,
      samples, hiddens, cb0, cb1, hb0, hb1, flagC, flagH);
}